// Round 3
// baseline (395.286 us; speedup 1.0000x reference)
//
#include <hip/hip_runtime.h>
#include <stdint.h>

// VQ-VAE vector quantizer — fp32 dataset, NCHW input [64,64,32,32], emb [1024,64].
// Key constraint: encodings must match np.argmin over the reference's fp32
// distance computation BIT-FOR-BIT (ref distances are quantized at ulp(64)
// ~3.8e-6; ~65/65536 points are quantized ties resolved by first-index).
// So we replicate numpy's exact fp32 expression tree:
//   d_k = fp32( fp32(A - 2*G_k) + C_k )
//   A   = np-pairwise sum (8 strided accs + tree) of fp32(x_d*x_d)
//   G_k = sequential fp32 FMA over d (BLAS sgemm microkernel order)
//   C_k = np-pairwise sum of fp32(e_d*e_d)
constexpr int KCODES = 1024;
constexpr int DDIM   = 64;
constexpr int HW     = 1024;
constexpr int NPTS   = 65536;

// d_out flat layout (fp32), reference return order
constexpr int OUT_Q    = 0;         // 4194304: straight-through fwd (NCHW)
constexpr int OUT_IDX  = 4194304;   // 65536:  encodings as float
constexpr int OUT_LOSS = 4259840;   // 1
constexpr int OUT_NLL  = 4259841;   // 1

// ws: [0..1023] C_k = ||e_k||^2 (np-pairwise) ; [1024] loss accumulator

// numpy pairwise_sum for n=64 contiguous fp32: r[j] = sum_{i=j,j+8,..,j+56} a[i]
// sequentially, then ((r0+r1)+(r2+r3)) + ((r4+r5)+(r6+r7)). All ops round-to-
// nearest fp32, no contraction (__fadd_rn/__fmul_rn are fusion-proof).
__device__ __forceinline__ float np_pairwise_sumsq64(const float* a) {
    float r[8];
    #pragma unroll
    for (int j = 0; j < 8; ++j) r[j] = __fmul_rn(a[j], a[j]);
    #pragma unroll
    for (int i = 8; i < 64; i += 8)
        #pragma unroll
        for (int j = 0; j < 8; ++j)
            r[j] = __fadd_rn(r[j], __fmul_rn(a[i + j], a[i + j]));
    return __fadd_rn(__fadd_rn(__fadd_rn(r[0], r[1]), __fadd_rn(r[2], r[3])),
                     __fadd_rn(__fadd_rn(r[4], r[5]), __fadd_rn(r[6], r[7])));
}

__global__ void vq_pre(const float* __restrict__ emb, float* __restrict__ ws) {
    int k = blockIdx.x * blockDim.x + threadIdx.x;
    if (k == 0) ws[KCODES] = 0.0f;                 // ws is poisoned 0xAA each call
    if (k < KCODES) {
        float row[DDIM];
        const float4* src = (const float4*)(emb + (size_t)k * DDIM);
        #pragma unroll
        for (int j = 0; j < 16; ++j) ((float4*)row)[j] = src[j];
        ws[k] = np_pairwise_sumsq64(row);          // C_k, full ||e||^2
    }
}

constexpr int KC = 128;   // codes per LDS chunk: 128*64 fp32 = 32 KB

__global__ __launch_bounds__(256, 1) void vq_main(
        const float* __restrict__ inp,    // [B=64][C=64][HW=1024] fp32 NCHW
        const float* __restrict__ emb,    // [K=1024][D=64] fp32
        const float* __restrict__ cws,    // C_k = ||e_k||^2 (np-pairwise)
        float*       __restrict__ loss_acc,
        float*       __restrict__ out)
{
    __shared__ float se[KC * DDIM];
    __shared__ float sc[KC];
    __shared__ float sred[4];

    const int tid = threadIdx.x;
    const int n   = blockIdx.x * 256 + tid;
    const int b   = n >> 10;
    const int hw  = n & (HW - 1);

    // x[d] = inp[b][d][hw] — coalesced across hw within a wave
    const float* xin = inp + (size_t)b * DDIM * HW + hw;
    float x[DDIM];
    #pragma unroll
    for (int d = 0; d < DDIM; ++d) x[d] = xin[(size_t)d * HW];

    // A = np.sum(x*x) with numpy's exact pairwise order
    const float A = np_pairwise_sumsq64(x);

    float best = 3.0e38f;
    int   bi   = 0;

    #pragma unroll 1
    for (int c = 0; c < KCODES; c += KC) {
        __syncthreads();
        // stage KC rows: 8192 contiguous floats, float4-coalesced
        const float4* src = (const float4*)(emb + (size_t)c * DDIM);
        float4* dst = (float4*)se;
        #pragma unroll
        for (int j = 0; j < 8; ++j) dst[j * 256 + tid] = src[j * 256 + tid];
        if (tid < KC) sc[tid] = cws[c + tid];
        __syncthreads();

        #pragma unroll 1
        for (int k = 0; k < KC; k += 4) {     // 4 independent FMA chains (ILP)
            const float* e0 = se + (k    ) * DDIM;  // wave-uniform -> LDS broadcast
            const float* e1 = se + (k + 1) * DDIM;
            const float* e2 = se + (k + 2) * DDIM;
            const float* e3 = se + (k + 3) * DDIM;
            // G_k: sequential fp32 FMA from 0 over d=0..63 (sgemm microkernel order)
            float g0 = 0.f, g1 = 0.f, g2 = 0.f, g3 = 0.f;
            #pragma unroll
            for (int d = 0; d < DDIM; ++d) {
                g0 = fmaf(x[d], e0[d], g0);
                g1 = fmaf(x[d], e1[d], g1);
                g2 = fmaf(x[d], e2[d], g2);
                g3 = fmaf(x[d], e3[d], g3);
            }
            // d_k = fp32( fp32(A - 2*G) + C ), ties -> lowest index (strict <, asc k)
            float d0 = __fadd_rn(__fsub_rn(A, __fmul_rn(2.0f, g0)), sc[k    ]);
            float d1 = __fadd_rn(__fsub_rn(A, __fmul_rn(2.0f, g1)), sc[k + 1]);
            float d2 = __fadd_rn(__fsub_rn(A, __fmul_rn(2.0f, g2)), sc[k + 2]);
            float d3 = __fadd_rn(__fsub_rn(A, __fmul_rn(2.0f, g3)), sc[k + 3]);
            if (d0 < best) { best = d0; bi = c + k; }
            if (d1 < best) { best = d1; bi = c + k + 1; }
            if (d2 < best) { best = d2; bi = c + k + 2; }
            if (d3 < best) { best = d3; bi = c + k + 3; }
        }
    }

    out[OUT_IDX + n] = (float)bi;

    // gather winning code row (rows 256B-aligned)
    float qrow[DDIM];
    const float4* q4 = (const float4*)(emb + (size_t)bi * DDIM);
    #pragma unroll
    for (int j = 0; j < 16; ++j) ((float4*)qrow)[j] = q4[j];

    // straight-through fwd: replicate ref rounding out = fp32(x + fp32(q - x));
    // loss partial from (q - x)^2
    float* orow = out + OUT_Q + (size_t)b * DDIM * HW + hw;
    float lacc = 0.f;
    #pragma unroll
    for (int d = 0; d < DDIM; ++d) {
        float q    = qrow[d];
        float diff = __fsub_rn(q, x[d]);
        orow[(size_t)d * HW] = __fadd_rn(x[d], diff);
        lacc = fmaf(diff, diff, lacc);
    }

    #pragma unroll
    for (int off = 32; off > 0; off >>= 1) lacc += __shfl_down(lacc, off, 64);
    if ((tid & 63) == 0) sred[tid >> 6] = lacc;
    __syncthreads();
    if (tid == 0) atomicAdd(loss_acc, sred[0] + sred[1] + sred[2] + sred[3]);
}

__global__ void vq_fin(const float* __restrict__ ws, float* __restrict__ out) {
    // loss = (1 + 0.25) * mean((q - x)^2), mean over N*D = 4194304 (2% tolerance)
    out[OUT_LOSS] = ws[KCODES] * (1.25f / 4194304.0f);
    out[OUT_NLL]  = 1.0f;
}

extern "C" void kernel_launch(void* const* d_in, const int* in_sizes, int n_in,
                              void* d_out, int out_size, void* d_ws, size_t ws_size,
                              hipStream_t stream) {
    const float* inp = (const float*)d_in[0];
    const float* emb = (const float*)d_in[1];
    float* out = (float*)d_out;
    float* ws  = (float*)d_ws;

    vq_pre<<<4, 256, 0, stream>>>(emb, ws);
    vq_main<<<NPTS / 256, 256, 0, stream>>>(inp, emb, ws, ws + KCODES, out);
    vq_fin<<<1, 1, 0, stream>>>(ws, out);
}

// Round 4
// 230.275 us; speedup vs baseline: 1.7166x; 1.7166x over previous
//
#include <hip/hip_runtime.h>
#include <stdint.h>

// VQ-VAE vector quantizer — fp32, NCHW input [64,64,32,32], emb [1024,64].
// Bit-exact replication of numpy's fp32 expression tree (proved: round 3
// passed with absmax 0.0):
//   d_k = fp32( fp32(A - 2*G_k) + C_k )
//   A,C = np-pairwise sums of squares; G_k = sequential fp32 FMA over d.
// Perf redesign vs round 3: round 3 was LDS-read-pipe bound (1 ds_read_b128
// per 4 wave-FMAs, ~13 cyc/b128 per CU => 786k cyc/CU vs 131k FMA floor).
// Now the codebook is read via wave-uniform scalar loads (SMEM pipe) into
// SGPRs, FMAs use the SGPR operand directly; splitK=4 across the block's
// waves raises occupancy 1 -> 4 waves/SIMD.
constexpr int KCODES = 1024;
constexpr int DDIM   = 64;
constexpr int HW     = 1024;
constexpr int NPTS   = 65536;

constexpr int OUT_Q    = 0;         // 4194304: straight-through fwd (NCHW)
constexpr int OUT_IDX  = 4194304;   // 65536:  encodings as float
constexpr int OUT_LOSS = 4259840;   // 1
constexpr int OUT_NLL  = 4259841;   // 1

// ws: [0..1023] C_k = ||e_k||^2 (np-pairwise) ; [1024] loss accumulator

__device__ __forceinline__ float np_pairwise_sumsq64(const float* a) {
    float r[8];
    #pragma unroll
    for (int j = 0; j < 8; ++j) r[j] = __fmul_rn(a[j], a[j]);
    #pragma unroll
    for (int i = 8; i < 64; i += 8)
        #pragma unroll
        for (int j = 0; j < 8; ++j)
            r[j] = __fadd_rn(r[j], __fmul_rn(a[i + j], a[i + j]));
    return __fadd_rn(__fadd_rn(__fadd_rn(r[0], r[1]), __fadd_rn(r[2], r[3])),
                     __fadd_rn(__fadd_rn(r[4], r[5]), __fadd_rn(r[6], r[7])));
}

__global__ void vq_pre(const float* __restrict__ emb, float* __restrict__ ws) {
    int k = blockIdx.x * blockDim.x + threadIdx.x;
    if (k == 0) ws[KCODES] = 0.0f;                 // ws is poisoned 0xAA each call
    if (k < KCODES) {
        float row[DDIM];
        const float4* src = (const float4*)(emb + (size_t)k * DDIM);
        #pragma unroll
        for (int j = 0; j < 16; ++j) ((float4*)row)[j] = src[j];
        ws[k] = np_pairwise_sumsq64(row);          // C_k
    }
}

// Block: 256 threads = 4 waves. Wave w handles codes [256w, 256w+256) for the
// block's 64 points (point = blockIdx*64 + lane). Grid 1024 => 4 blocks/CU,
// 16 waves/CU. LDS only for the splitK combine (~2.3 KB).
__global__ __launch_bounds__(256, 4) void vq_main(
        const float* __restrict__ inp,    // [64][64][1024] fp32 NCHW
        const float* __restrict__ emb_,   // [1024][64] fp32
        const float* __restrict__ cws_,   // C_k
        float*       __restrict__ loss_acc,
        float*       __restrict__ out)
{
    const float* emb = (const float*)__builtin_assume_aligned(emb_, 256);
    const float* cws = (const float*)__builtin_assume_aligned(cws_, 256);

    __shared__ float rbest[256];
    __shared__ int   rbi[256];
    __shared__ int   sbi[64];
    __shared__ float sred[4];

    const int tid  = threadIdx.x;
    const int lane = tid & 63;
    const int wave = __builtin_amdgcn_readfirstlane(tid >> 6);  // provably uniform

    const int n  = blockIdx.x * 64 + lane;   // point id
    const int b  = n >> 10;
    const int hw = n & (HW - 1);

    // x[d] = inp[b][d][hw]; lanes -> consecutive hw => 256B coalesced per d.
    const float* xin = inp + (size_t)b * DDIM * HW + hw;
    float x[DDIM];
    #pragma unroll
    for (int d = 0; d < DDIM; ++d) x[d] = xin[(size_t)d * HW];

    const float A = np_pairwise_sumsq64(x);

    // Scan this wave's 256-code slice. e-row address is wave-uniform =>
    // scalar loads (SMEM) feeding v_fma with the SGPR operand; VALU does
    // exactly one fp32 FMA per (code,d) in sequential d order (bit-exact).
    const int    k0 = wave * 256;
    const float* eb = emb + (size_t)k0 * DDIM;
    float best = 3.0e38f;
    int   bi   = k0;

    #pragma unroll 1
    for (int k = 0; k < 256; ++k) {
        const float* er = eb + (size_t)k * DDIM;   // uniform
        float g = 0.f;
        #pragma unroll
        for (int d = 0; d < DDIM; ++d) g = fmaf(x[d], er[d], g);
        float dk = __fadd_rn(__fsub_rn(A, __fmul_rn(2.0f, g)), cws[k0 + k]);
        if (dk < best) { best = dk; bi = k0 + k; }  // strict < => first-min
    }

    rbest[tid] = best;
    rbi[tid]   = bi;
    __syncthreads();

    // Combine the 4 slice winners per point; ascending slice + strict < keeps
    // the lowest code index on quantized ties (matches np.argmin).
    if (tid < 64) {
        float bb = rbest[tid];
        int   ii = rbi[tid];
        #pragma unroll
        for (int s = 1; s < 4; ++s) {
            float c  = rbest[s * 64 + tid];
            int   ci = rbi[s * 64 + tid];
            if (c < bb) { bb = c; ii = ci; }
        }
        out[OUT_IDX + n] = (float)ii;
        sbi[tid] = ii;
    }
    __syncthreads();

    // Epilogue split across waves: wave w writes channels [16w,16w+16).
    const int mybi = sbi[lane];
    const int db   = wave * 16;
    float q[16];
    const float4* q4 = (const float4*)(emb + (size_t)mybi * DDIM + db);
    #pragma unroll
    for (int j = 0; j < 4; ++j) ((float4*)q)[j] = q4[j];

    float* orow = out + OUT_Q + (size_t)b * DDIM * HW + hw;
    float lacc = 0.f;
    #pragma unroll
    for (int j = 0; j < 16; ++j) {
        int   d    = db + j;
        float diff = __fsub_rn(q[j], x[d]);
        orow[(size_t)d * HW] = __fadd_rn(x[d], diff);   // ref's x + (q - x) rounding
        lacc = fmaf(diff, diff, lacc);
    }

    #pragma unroll
    for (int off = 32; off > 0; off >>= 1) lacc += __shfl_down(lacc, off, 64);
    if (lane == 0) sred[wave] = lacc;
    __syncthreads();
    if (tid == 0) atomicAdd(loss_acc, sred[0] + sred[1] + sred[2] + sred[3]);
}

__global__ void vq_fin(const float* __restrict__ ws, float* __restrict__ out) {
    out[OUT_LOSS] = ws[KCODES] * (1.25f / 4194304.0f);   // (1+CC)*mean((q-x)^2)
    out[OUT_NLL]  = 1.0f;
}

extern "C" void kernel_launch(void* const* d_in, const int* in_sizes, int n_in,
                              void* d_out, int out_size, void* d_ws, size_t ws_size,
                              hipStream_t stream) {
    const float* inp = (const float*)d_in[0];
    const float* emb = (const float*)d_in[1];
    float* out = (float*)d_out;
    float* ws  = (float*)d_ws;

    vq_pre<<<4, 256, 0, stream>>>(emb, ws);
    vq_main<<<NPTS / 64, 256, 0, stream>>>(inp, emb, ws, ws + KCODES, out);
    vq_fin<<<1, 1, 0, stream>>>(ws, out);
}